// Round 5
// baseline (3709.704 us; speedup 1.0000x reference)
//
#include <hip/hip_runtime.h>

#define HIDN 128
#define TILE 16            // samples per block
#define ROWS 8             // hidden rows per thread (16 threads per sample)
#define VROWB 2064         // bytes per sample row in v-buffers (129 float4 slots: pad -> s-groups on distinct banks)
#define ASTR 132           // floats per sample row in abuf
#define JSTR 17            // floats per sample row in jf

// Byte offset of v[s][j] (a float4 = 4 tangent cols for hidden unit j).
// XOR swizzle folds j[3:5] into the bank bits so the 128B-stride stores from
// the 16 threads of one sample are 2-way (free) instead of 16-way conflicted.
// Bijective within a row; reads (same j across a sample's threads) broadcast.
__device__ __forceinline__ int vidx(int s, int j) {
    return s * VROWB + ((j * 16) ^ ((j & 0x38) << 1));
}

__global__ __launch_bounds__(256, 2)
void wnn_jac_kernel(const float* __restrict__ u,
                    const float* __restrict__ W1, const float* __restrict__ b1,
                    const float* __restrict__ W2, const float* __restrict__ b2,
                    const float* __restrict__ W3, const float* __restrict__ b3,
                    const float* __restrict__ W4,
                    float* __restrict__ out, int Btot)
{
    __shared__ __align__(16) unsigned char vAraw[TILE * VROWB];
    __shared__ __align__(16) unsigned char vBraw[TILE * VROWB];
    __shared__ __align__(16) float abuf[TILE * ASTR];
    __shared__ float jf[TILE * JSTR];

    const int tid = threadIdx.x;
    const int s   = tid >> 4;          // sample within tile
    const int r   = tid & 15;          // row group within sample
    const int i0  = r * ROWS;
    const long sg = (long)blockIdx.x * TILE + s;
    const bool valid = (sg < (long)Btot);

    float4 uv = make_float4(0.f, 0.f, 0.f, 0.f);
    if (valid) uv = *(const float4*)(u + sg * 4);

    unsigned m1 = 0, m2 = 0, m3 = 0;

    // ---------- forward layer 1: h = (seq-fma chain from 0) + b (bit-exact vs np/BLAS) ----------
    #pragma unroll
    for (int ii = 0; ii < ROWS; ++ii) {
        const int i = i0 + ii;
        const float4 w = *(const float4*)(W1 + i * 4);
        float h = 0.f;
        h = fmaf(w.x, uv.x, h);
        h = fmaf(w.y, uv.y, h);
        h = fmaf(w.z, uv.z, h);
        h = fmaf(w.w, uv.w, h);
        h = h + b1[i];
        if (h > 0.f) m1 |= (1u << ii);
        abuf[s * ASTR + i] = fmaxf(h, 0.f);
    }
    __syncthreads();

    // ---------- forward layer 2 (seq-k per row, bias after) ----------
    {
        float acc[ROWS];
        #pragma unroll
        for (int ii = 0; ii < ROWS; ++ii) acc[ii] = 0.f;
        const float* arow = abuf + s * ASTR;
        #pragma unroll 2
        for (int jc = 0; jc < 32; ++jc) {
            const float4 av = *(const float4*)(arow + jc * 4);
            #pragma unroll
            for (int ii = 0; ii < ROWS; ++ii) {
                const float4 w = *(const float4*)(W2 + (i0 + ii) * HIDN + jc * 4);
                float a = acc[ii];
                a = fmaf(w.x, av.x, a);
                a = fmaf(w.y, av.y, a);
                a = fmaf(w.z, av.z, a);
                a = fmaf(w.w, av.w, a);
                acc[ii] = a;
            }
        }
        __syncthreads();   // all a1 reads complete before overwriting abuf with a2
        #pragma unroll
        for (int ii = 0; ii < ROWS; ++ii) {
            const float h = acc[ii] + b2[i0 + ii];
            if (h > 0.f) m2 |= (1u << ii);
            abuf[s * ASTR + i0 + ii] = fmaxf(h, 0.f);
        }
    }
    __syncthreads();

    // ---------- forward layer 3 (mask only) ----------
    {
        float acc[ROWS];
        #pragma unroll
        for (int ii = 0; ii < ROWS; ++ii) acc[ii] = 0.f;
        const float* arow = abuf + s * ASTR;
        #pragma unroll 2
        for (int jc = 0; jc < 32; ++jc) {
            const float4 av = *(const float4*)(arow + jc * 4);
            #pragma unroll
            for (int ii = 0; ii < ROWS; ++ii) {
                const float4 w = *(const float4*)(W3 + (i0 + ii) * HIDN + jc * 4);
                float a = acc[ii];
                a = fmaf(w.x, av.x, a);
                a = fmaf(w.y, av.y, a);
                a = fmaf(w.z, av.z, a);
                a = fmaf(w.w, av.w, a);
                acc[ii] = a;
            }
        }
        #pragma unroll
        for (int ii = 0; ii < ROWS; ++ii) {
            const float h = acc[ii] + b3[i0 + ii];
            if (h > 0.f) m3 |= (1u << ii);
        }
    }

    // ---------- v1 = m1 ⊙ W1 (all 4 tangent cols at once) -> vA ----------
    #pragma unroll
    for (int ii = 0; ii < ROWS; ++ii) {
        const int j = i0 + ii;
        const float4 w = *(const float4*)(W1 + j * 4);
        const float4 z = make_float4(0.f, 0.f, 0.f, 0.f);
        *(float4*)(vAraw + vidx(s, j)) = ((m1 >> ii) & 1u) ? w : z;
    }
    __syncthreads();

    // ---------- v2 = m2 ⊙ (W2 @ v1) : vA -> vB (fused over 4 cols) ----------
    {
        float acc[ROWS][4];
        #pragma unroll
        for (int ii = 0; ii < ROWS; ++ii)
            #pragma unroll
            for (int k = 0; k < 4; ++k) acc[ii][k] = 0.f;
        #pragma unroll 1
        for (int jc = 0; jc < 32; ++jc) {
            const float4 pv0 = *(const float4*)(vAraw + vidx(s, jc * 4 + 0));
            const float4 pv1 = *(const float4*)(vAraw + vidx(s, jc * 4 + 1));
            const float4 pv2 = *(const float4*)(vAraw + vidx(s, jc * 4 + 2));
            const float4 pv3 = *(const float4*)(vAraw + vidx(s, jc * 4 + 3));
            #pragma unroll
            for (int ii = 0; ii < ROWS; ++ii) {
                const float4 w = *(const float4*)(W2 + (i0 + ii) * HIDN + jc * 4);
                acc[ii][0] = fmaf(w.x, pv0.x, acc[ii][0]);
                acc[ii][1] = fmaf(w.x, pv0.y, acc[ii][1]);
                acc[ii][2] = fmaf(w.x, pv0.z, acc[ii][2]);
                acc[ii][3] = fmaf(w.x, pv0.w, acc[ii][3]);
                acc[ii][0] = fmaf(w.y, pv1.x, acc[ii][0]);
                acc[ii][1] = fmaf(w.y, pv1.y, acc[ii][1]);
                acc[ii][2] = fmaf(w.y, pv1.z, acc[ii][2]);
                acc[ii][3] = fmaf(w.y, pv1.w, acc[ii][3]);
                acc[ii][0] = fmaf(w.z, pv2.x, acc[ii][0]);
                acc[ii][1] = fmaf(w.z, pv2.y, acc[ii][1]);
                acc[ii][2] = fmaf(w.z, pv2.z, acc[ii][2]);
                acc[ii][3] = fmaf(w.z, pv2.w, acc[ii][3]);
                acc[ii][0] = fmaf(w.w, pv3.x, acc[ii][0]);
                acc[ii][1] = fmaf(w.w, pv3.y, acc[ii][1]);
                acc[ii][2] = fmaf(w.w, pv3.z, acc[ii][2]);
                acc[ii][3] = fmaf(w.w, pv3.w, acc[ii][3]);
            }
        }
        #pragma unroll
        for (int ii = 0; ii < ROWS; ++ii) {
            const bool on = ((m2 >> ii) & 1u) != 0u;
            float4 o;
            o.x = on ? acc[ii][0] : 0.f;
            o.y = on ? acc[ii][1] : 0.f;
            o.z = on ? acc[ii][2] : 0.f;
            o.w = on ? acc[ii][3] : 0.f;
            *(float4*)(vBraw + vidx(s, i0 + ii)) = o;
        }
    }
    __syncthreads();

    // ---------- v3 = m3 ⊙ (W3 @ v2) : vB -> vA ----------
    {
        float acc[ROWS][4];
        #pragma unroll
        for (int ii = 0; ii < ROWS; ++ii)
            #pragma unroll
            for (int k = 0; k < 4; ++k) acc[ii][k] = 0.f;
        #pragma unroll 1
        for (int jc = 0; jc < 32; ++jc) {
            const float4 pv0 = *(const float4*)(vBraw + vidx(s, jc * 4 + 0));
            const float4 pv1 = *(const float4*)(vBraw + vidx(s, jc * 4 + 1));
            const float4 pv2 = *(const float4*)(vBraw + vidx(s, jc * 4 + 2));
            const float4 pv3 = *(const float4*)(vBraw + vidx(s, jc * 4 + 3));
            #pragma unroll
            for (int ii = 0; ii < ROWS; ++ii) {
                const float4 w = *(const float4*)(W3 + (i0 + ii) * HIDN + jc * 4);
                acc[ii][0] = fmaf(w.x, pv0.x, acc[ii][0]);
                acc[ii][1] = fmaf(w.x, pv0.y, acc[ii][1]);
                acc[ii][2] = fmaf(w.x, pv0.z, acc[ii][2]);
                acc[ii][3] = fmaf(w.x, pv0.w, acc[ii][3]);
                acc[ii][0] = fmaf(w.y, pv1.x, acc[ii][0]);
                acc[ii][1] = fmaf(w.y, pv1.y, acc[ii][1]);
                acc[ii][2] = fmaf(w.y, pv1.z, acc[ii][2]);
                acc[ii][3] = fmaf(w.y, pv1.w, acc[ii][3]);
                acc[ii][0] = fmaf(w.z, pv2.x, acc[ii][0]);
                acc[ii][1] = fmaf(w.z, pv2.y, acc[ii][1]);
                acc[ii][2] = fmaf(w.z, pv2.z, acc[ii][2]);
                acc[ii][3] = fmaf(w.z, pv2.w, acc[ii][3]);
                acc[ii][0] = fmaf(w.w, pv3.x, acc[ii][0]);
                acc[ii][1] = fmaf(w.w, pv3.y, acc[ii][1]);
                acc[ii][2] = fmaf(w.w, pv3.z, acc[ii][2]);
                acc[ii][3] = fmaf(w.w, pv3.w, acc[ii][3]);
            }
        }
        #pragma unroll
        for (int ii = 0; ii < ROWS; ++ii) {
            const bool on = ((m3 >> ii) & 1u) != 0u;
            float4 o;
            o.x = on ? acc[ii][0] : 0.f;
            o.y = on ? acc[ii][1] : 0.f;
            o.z = on ? acc[ii][2] : 0.f;
            o.w = on ? acc[ii][3] : 0.f;
            *(float4*)(vAraw + vidx(s, i0 + ii)) = o;
        }
    }
    __syncthreads();

    // ---------- Jf[c][:] = W4[c,:] @ v3 (threads r<4, c=r) ----------
    if (r < 4) {
        float a0 = 0.f, a1v = 0.f, a2v = 0.f, a3v = 0.f;
        #pragma unroll 2
        for (int jc = 0; jc < 32; ++jc) {
            const float4 pv0 = *(const float4*)(vAraw + vidx(s, jc * 4 + 0));
            const float4 pv1 = *(const float4*)(vAraw + vidx(s, jc * 4 + 1));
            const float4 pv2 = *(const float4*)(vAraw + vidx(s, jc * 4 + 2));
            const float4 pv3 = *(const float4*)(vAraw + vidx(s, jc * 4 + 3));
            const float4 w = *(const float4*)(W4 + r * HIDN + jc * 4);
            a0 = fmaf(w.x, pv0.x, a0); a1v = fmaf(w.x, pv0.y, a1v);
            a2v = fmaf(w.x, pv0.z, a2v); a3v = fmaf(w.x, pv0.w, a3v);
            a0 = fmaf(w.y, pv1.x, a0); a1v = fmaf(w.y, pv1.y, a1v);
            a2v = fmaf(w.y, pv1.z, a2v); a3v = fmaf(w.y, pv1.w, a3v);
            a0 = fmaf(w.z, pv2.x, a0); a1v = fmaf(w.z, pv2.y, a1v);
            a2v = fmaf(w.z, pv2.z, a2v); a3v = fmaf(w.z, pv2.w, a3v);
            a0 = fmaf(w.w, pv3.x, a0); a1v = fmaf(w.w, pv3.y, a1v);
            a2v = fmaf(w.w, pv3.z, a2v); a3v = fmaf(w.w, pv3.w, a3v);
        }
        float4 o = make_float4(a0, a1v, a2v, a3v);
        *(float4*)(&jf[s * JSTR + r * 4]) = o;   // jf[s][c=r][k]
    }
    __syncthreads();

    // ---------- epilogue: out[b][g][c] = Jf[b][c][g] - Jf[b][g][c] ----------
    if (valid && r < 4) {
        const float* jrow = jf + s * JSTR;
        float4 o;
        o.x = jrow[0 * 4 + r] - jrow[r * 4 + 0];
        o.y = jrow[1 * 4 + r] - jrow[r * 4 + 1];
        o.z = jrow[2 * 4 + r] - jrow[r * 4 + 2];
        o.w = jrow[3 * 4 + r] - jrow[r * 4 + 3];
        *(float4*)(out + sg * 16 + r * 4) = o;
    }
}

extern "C" void kernel_launch(void* const* d_in, const int* in_sizes, int n_in,
                              void* d_out, int out_size, void* d_ws, size_t ws_size,
                              hipStream_t stream)
{
    const float* u  = (const float*)d_in[0];
    const float* W1 = (const float*)d_in[1];
    const float* b1 = (const float*)d_in[2];
    const float* W2 = (const float*)d_in[3];
    const float* b2 = (const float*)d_in[4];
    const float* W3 = (const float*)d_in[5];
    const float* b3 = (const float*)d_in[6];
    const float* W4 = (const float*)d_in[7];
    // d_in[8] = b4: unused (bias does not enter the Jacobian)
    float* out = (float*)d_out;

    const int B = in_sizes[0] / 4;
    const int nblocks = (B + TILE - 1) / TILE;
    hipLaunchKernelGGL(wnn_jac_kernel, dim3(nblocks), dim3(256), 0, stream,
                       u, W1, b1, W2, b2, W3, b3, W4, out, B);
}

// Round 7
// 769.225 us; speedup vs baseline: 4.8227x; 4.8227x over previous
//
#include <hip/hip_runtime.h>

#define HIDN 128
#define SAMP 32            // samples per block
#define VSTR 272           // V-buffer row stride in BYTES (17x16B pad -> conflict-free b128 reads)
#define ASTR 132           // f32 activation row stride (floats)

typedef __attribute__((ext_vector_type(8))) short short8;
typedef __attribute__((ext_vector_type(4))) float f32x4;

// f32 -> bf16 round-to-nearest-even
__device__ __forceinline__ unsigned short f2bf(float f) {
    unsigned b = __float_as_uint(f);
    b += 0x7FFFu + ((b >> 16) & 1u);
    return (unsigned short)(b >> 16);
}

// convert 8 consecutive f32 to a bf16x8 fragment
__device__ __forceinline__ short8 cvt_row8(const float* __restrict__ p) {
    const float4 lo = *(const float4*)p;
    const float4 hi = *(const float4*)(p + 4);
    short8 fr;
    fr[0] = (short)f2bf(lo.x); fr[1] = (short)f2bf(lo.y);
    fr[2] = (short)f2bf(lo.z); fr[3] = (short)f2bf(lo.w);
    fr[4] = (short)f2bf(hi.x); fr[5] = (short)f2bf(hi.y);
    fr[6] = (short)f2bf(hi.z); fr[7] = (short)f2bf(hi.w);
    return fr;
}

// One tangent layer: dst[sc][i] = mask[s(sc)][i] * sum_j src[sc][j] * W[i][j].
// src != dst (ping/pong) -> no in-place hazards. Rows are wave-private.
// Lane roles: lr = lane&15 (A-row / B-col), lk = lane>>4 (k-group).
__device__ __forceinline__ void tangent_layer(const unsigned char* __restrict__ src,
                                              unsigned char* __restrict__ dst,
                                              const float* __restrict__ W,
                                              const unsigned short* __restrict__ msk, // [32][8]
                                              int wv, int lr, int lk)
{
    #pragma unroll
    for (int ib = 0; ib < 8; ++ib) {
        // B fragments for output units [ib*16, ib*16+16): B[k][n=lr] = W[ib*16+lr][k]
        short8 bfr[4];
        #pragma unroll
        for (int ks = 0; ks < 4; ++ks)
            bfr[ks] = cvt_row8(W + (ib * 16 + lr) * HIDN + ks * 32 + lk * 8);
        #pragma unroll
        for (int q = 0; q < 2; ++q) {
            const int sc0 = wv * 32 + q * 16;
            f32x4 c = (f32x4){0.f, 0.f, 0.f, 0.f};
            #pragma unroll
            for (int ks = 0; ks < 4; ++ks) {
                const short8 a = *(const short8*)(src + (sc0 + lr) * VSTR + ks * 64 + lk * 16);
                c = __builtin_amdgcn_mfma_f32_16x16x32_bf16(a, bfr[ks], c, 0, 0, 0);
            }
            // D rows m = lk*4+r -> sc = sc0+lk*4+r (all same sample), col n = lr -> unit ib*16+lr
            const int sm = (sc0 >> 2) + lk;
            const unsigned bit = (msk[sm * 8 + ib] >> lr) & 1u;
            #pragma unroll
            for (int r = 0; r < 4; ++r) {
                const float v = bit ? c[r] : 0.f;
                *(unsigned short*)(dst + (sc0 + lk * 4 + r) * VSTR + (ib * 16 + lr) * 2) = f2bf(v);
            }
        }
    }
}

__global__ __launch_bounds__(256, 2)
void wnn_jac_kernel(const float* __restrict__ u,
                    const float* __restrict__ W1, const float* __restrict__ b1,
                    const float* __restrict__ W2, const float* __restrict__ b2,
                    const float* __restrict__ W3, const float* __restrict__ b3,
                    const float* __restrict__ W4,
                    float* __restrict__ out, int Btot)
{
    __shared__ __align__(16) unsigned char vping[128 * VSTR];  // 34816 B
    __shared__ __align__(16) unsigned char vpong[128 * VSTR];
    __shared__ unsigned short mlds[3][SAMP][8];                // per-(sample, 16-row group) masks
    __shared__ float jbuf[128 * 5];                            // Jf scratch [sc][c'], stride 5

    float* abufA = (float*)vping;   // forward a1, f32 [32][132] (aliased; sync-separated)
    float* abufB = (float*)vpong;   // forward a2

    const int tid  = threadIdx.x;
    const int s    = tid & 31;      // sample (forward phase)
    const int gg   = tid >> 5;      // row group 0..7 (16 rows each)
    const int i0   = gg * 16;
    const long sg0 = (long)blockIdx.x * SAMP;
    const bool valid = (sg0 + s < (long)Btot);

    float4 uv = make_float4(0.f, 0.f, 0.f, 0.f);
    if (valid) uv = *(const float4*)(u + (sg0 + s) * 4);

    // ======== forward layer 1 (bit-exact: seq f32 fma chain from 0, bias after) ========
    {
        unsigned short m = 0;
        #pragma unroll
        for (int ii = 0; ii < 16; ++ii) {
            const int i = i0 + ii;
            const float4 w = *(const float4*)(W1 + i * 4);
            float h = 0.f;
            h = fmaf(w.x, uv.x, h);
            h = fmaf(w.y, uv.y, h);
            h = fmaf(w.z, uv.z, h);
            h = fmaf(w.w, uv.w, h);
            h = h + b1[i];
            if (h > 0.f) m |= (unsigned short)(1u << ii);
            abufA[s * ASTR + i] = fmaxf(h, 0.f);
        }
        mlds[0][s][gg] = m;
    }
    __syncthreads();

    // ======== forward layer 2 ========
    {
        float acc[16];
        #pragma unroll
        for (int ii = 0; ii < 16; ++ii) acc[ii] = 0.f;
        const float* arow = abufA + s * ASTR;
        #pragma unroll 2
        for (int jc = 0; jc < 32; ++jc) {
            const float4 av = *(const float4*)(arow + jc * 4);
            #pragma unroll
            for (int ii = 0; ii < 16; ++ii) {
                const float4 w = *(const float4*)(W2 + (i0 + ii) * HIDN + jc * 4);
                float a = acc[ii];
                a = fmaf(w.x, av.x, a);
                a = fmaf(w.y, av.y, a);
                a = fmaf(w.z, av.z, a);
                a = fmaf(w.w, av.w, a);
                acc[ii] = a;
            }
        }
        unsigned short m = 0;
        #pragma unroll
        for (int ii = 0; ii < 16; ++ii) {
            const float h = acc[ii] + b2[i0 + ii];
            if (h > 0.f) m |= (unsigned short)(1u << ii);
            abufB[s * ASTR + i0 + ii] = fmaxf(h, 0.f);   // different buffer: no WAR on abufA
        }
        mlds[1][s][gg] = m;
    }
    __syncthreads();

    // ======== forward layer 3 (mask only) ========
    {
        float acc[16];
        #pragma unroll
        for (int ii = 0; ii < 16; ++ii) acc[ii] = 0.f;
        const float* arow = abufB + s * ASTR;
        #pragma unroll 2
        for (int jc = 0; jc < 32; ++jc) {
            const float4 av = *(const float4*)(arow + jc * 4);
            #pragma unroll
            for (int ii = 0; ii < 16; ++ii) {
                const float4 w = *(const float4*)(W3 + (i0 + ii) * HIDN + jc * 4);
                float a = acc[ii];
                a = fmaf(w.x, av.x, a);
                a = fmaf(w.y, av.y, a);
                a = fmaf(w.z, av.z, a);
                a = fmaf(w.w, av.w, a);
                acc[ii] = a;
            }
        }
        unsigned short m = 0;
        #pragma unroll
        for (int ii = 0; ii < 16; ++ii) {
            const float h = acc[ii] + b3[i0 + ii];
            if (h > 0.f) m |= (unsigned short)(1u << ii);
        }
        mlds[2][s][gg] = m;
    }
    __syncthreads();   // abufB (=vpong) reads done; abufA (=vping) reads done since L2

    // ======== v1 build: vping row sc=s*4+c holds bf16 of m1[s][j]*W1[j][c] ========
    {
        const int row = tid >> 1, kh = tid & 1;      // 128 rows, 2 threads/row (k-halves)
        const int vs = row >> 2, vc = row & 3;
        #pragma unroll
        for (int j0 = kh * 64; j0 < kh * 64 + 64; j0 += 8) {
            short8 fr;
            #pragma unroll
            for (int e = 0; e < 8; ++e) {
                const int j = j0 + e;
                const unsigned bit = (mlds[0][vs][j >> 4] >> (j & 15)) & 1u;
                fr[e] = bit ? (short)f2bf(W1[j * 4 + vc]) : (short)0;
            }
            *(short8*)(vping + row * VSTR + j0 * 2) = fr;
        }
    }
    __syncthreads();

    const int lane = tid & 63, wv = tid >> 6;
    const int lr = lane & 15, lk = lane >> 4;

    // ======== tangent layers (ping -> pong -> ping) ========
    tangent_layer(vping, vpong, W2, &mlds[1][0][0], wv, lr, lk);
    __syncthreads();
    tangent_layer(vpong, vping, W3, &mlds[2][0][0], wv, lr, lk);
    __syncthreads();

    // ======== Jf: D[sc][c'] = sum_j V3[sc][j] * W4[c'][j] (cols 4..15 zero) ========
    {
        short8 b4[4];
        #pragma unroll
        for (int ks = 0; ks < 4; ++ks) {
            short8 fr = (short8){0, 0, 0, 0, 0, 0, 0, 0};
            if (lr < 4) fr = cvt_row8(W4 + lr * HIDN + ks * 32 + lk * 8);
            b4[ks] = fr;
        }
        #pragma unroll
        for (int q = 0; q < 2; ++q) {
            const int sc0 = wv * 32 + q * 16;
            f32x4 c = (f32x4){0.f, 0.f, 0.f, 0.f};
            #pragma unroll
            for (int ks = 0; ks < 4; ++ks) {
                const short8 a = *(const short8*)(vping + (sc0 + lr) * VSTR + ks * 64 + lk * 16);
                c = __builtin_amdgcn_mfma_f32_16x16x32_bf16(a, b4[ks], c, 0, 0, 0);
            }
            if (lr < 4) {
                #pragma unroll
                for (int r = 0; r < 4; ++r)
                    jbuf[(sc0 + lk * 4 + r) * 5 + lr] = c[r];   // Jf[c'=lr][c=sc&3] for sample sc>>2
            }
        }
    }
    __syncthreads();

    // ======== epilogue: out[s][a][b] = Jf[b][a] - Jf[a][b]; Jf[c'][c] = jbuf[(s*4+c)*5+c'] ========
    if (tid < 128) {
        const int es = tid >> 2, ea = tid & 3;
        if (sg0 + es < (long)Btot) {
            float4 o;
            o.x = jbuf[(es * 4 + ea) * 5 + 0] - jbuf[(es * 4 + 0) * 5 + ea];
            o.y = jbuf[(es * 4 + ea) * 5 + 1] - jbuf[(es * 4 + 1) * 5 + ea];
            o.z = jbuf[(es * 4 + ea) * 5 + 2] - jbuf[(es * 4 + 2) * 5 + ea];
            o.w = jbuf[(es * 4 + ea) * 5 + 3] - jbuf[(es * 4 + 3) * 5 + ea];
            *(float4*)(out + (sg0 + es) * 16 + ea * 4) = o;
        }
    }
}

extern "C" void kernel_launch(void* const* d_in, const int* in_sizes, int n_in,
                              void* d_out, int out_size, void* d_ws, size_t ws_size,
                              hipStream_t stream)
{
    const float* u  = (const float*)d_in[0];
    const float* W1 = (const float*)d_in[1];
    const float* b1 = (const float*)d_in[2];
    const float* W2 = (const float*)d_in[3];
    const float* b2 = (const float*)d_in[4];
    const float* W3 = (const float*)d_in[5];
    const float* b3 = (const float*)d_in[6];
    const float* W4 = (const float*)d_in[7];
    // d_in[8] = b4: unused (bias does not enter the Jacobian)
    float* out = (float*)d_out;

    const int B = in_sizes[0] / 4;
    const int nblocks = (B + SAMP - 1) / SAMP;
    hipLaunchKernelGGL(wnn_jac_kernel, dim3(nblocks), dim3(256), 0, stream,
                       u, W1, b1, W2, b2, W3, b3, W4, out, B);
}

// Round 9
// 712.003 us; speedup vs baseline: 5.2102x; 1.0804x over previous
//
#include <hip/hip_runtime.h>

#define HIDN 128
#define SAMP 16            // samples per block
#define VSTR 272           // V-buffer row stride in BYTES (17x16B -> conflict-free b128)
#define ASTR 132           // f32 activation row stride (floats)

typedef __attribute__((ext_vector_type(8))) short short8;
typedef __attribute__((ext_vector_type(4))) float f32x4;

// ws layout (ushort units): [0,16384) W2b[128][128]; [16384,32768) W3b[128][128];
// [32768,34816) W4b[16][128] (rows 4..15 zero); [34816,35328) W1Tb[4][128]
#define WS_W2 0
#define WS_W3 16384
#define WS_W4 32768
#define WS_W1T 34816
#define WS_TOT 35328

// f32 -> bf16 round-to-nearest-even
__device__ __forceinline__ unsigned short f2bf(float f) {
    unsigned b = __float_as_uint(f);
    b += 0x7FFFu + ((b >> 16) & 1u);
    return (unsigned short)(b >> 16);
}

// ---------- prelude: one-time weight conversion to bf16 into ws ----------
__global__ void conv_w_kernel(const float* __restrict__ W1, const float* __restrict__ W2,
                              const float* __restrict__ W3, const float* __restrict__ W4,
                              unsigned short* __restrict__ wsb)
{
    const int idx = blockIdx.x * 256 + threadIdx.x;
    if (idx < 16384) {
        wsb[idx] = f2bf(W2[idx]);
    } else if (idx < 32768) {
        wsb[idx] = f2bf(W3[idx - 16384]);
    } else if (idx < 34816) {
        const int r = (idx - 32768) >> 7, j = (idx - 32768) & 127;
        wsb[idx] = (r < 4) ? f2bf(W4[r * HIDN + j]) : (unsigned short)0;
    } else if (idx < WS_TOT) {
        const int c = (idx - 34816) >> 7, j = (idx - 34816) & 127;
        wsb[idx] = f2bf(W1[j * 4 + c]);
    }
}

// One tangent layer, PING-PONG (src != dst; in-place corrupts — R6/R8 lesson).
// Wave owns V rows [wv*16, wv*16+16). A = W rows (bf16 from ws), B = V cols.
// D[m=unit ib*16+lk*4+r][n=sc=wv*16+lr] -> one b64 store per (ib).
__device__ __forceinline__ void tangent_layer(const unsigned char* __restrict__ src,
                                              unsigned char* __restrict__ dst,
                                              const unsigned short* __restrict__ Wb,
                                              const unsigned char* __restrict__ msk, // [16][16]
                                              int wv, int lr, int lk)
{
    short8 b[4];
    #pragma unroll
    for (int ks = 0; ks < 4; ++ks)
        b[ks] = *(const short8*)(src + (wv * 16 + lr) * VSTR + ks * 64 + lk * 16);

    const int sc = wv * 16 + lr;
    #pragma unroll
    for (int ib = 0; ib < 8; ++ib) {
        short8 a[4];
        #pragma unroll
        for (int ks = 0; ks < 4; ++ks)
            a[ks] = *(const short8*)(Wb + (ib * 16 + lr) * HIDN + ks * 32 + lk * 8);
        f32x4 c = (f32x4){0.f, 0.f, 0.f, 0.f};
        #pragma unroll
        for (int ks = 0; ks < 4; ++ks)
            c = __builtin_amdgcn_mfma_f32_16x16x32_bf16(a[ks], b[ks], c, 0, 0, 0);
        // units i = ib*16 + lk*4 + r ; mask byte (i>>3), bit (i&7)
        const unsigned bits = (msk[(sc >> 2) * 16 + ib * 2 + (lk >> 1)] >> ((lk & 1) * 4)) & 0xFu;
        unsigned long long pk = 0;
        #pragma unroll
        for (int r = 0; r < 4; ++r) {
            const unsigned short v = ((bits >> r) & 1u) ? f2bf(c[r]) : (unsigned short)0;
            pk |= (unsigned long long)v << (r * 16);
        }
        *(unsigned long long*)(dst + sc * VSTR + ib * 32 + lk * 8) = pk;
    }
}

__global__ __launch_bounds__(256, 4)
void wnn_jac_kernel(const float* __restrict__ u,
                    const float* __restrict__ W1, const float* __restrict__ b1,
                    const float* __restrict__ W2, const float* __restrict__ b2,
                    const float* __restrict__ W3, const float* __restrict__ b3,
                    const unsigned short* __restrict__ wsb,
                    float* __restrict__ out, int Btot)
{
    __shared__ __align__(16) unsigned char vA[64 * VSTR];   // 17408 B
    __shared__ __align__(16) unsigned char vB[64 * VSTR];   // 17408 B
    __shared__ unsigned char mlds[3][SAMP][16];             // 768 B: [layer][sample][unit>>3]
    __shared__ float jbuf[64 * 5];                          // 1280 B  -> total 36864 B, 4 blocks/CU

    float* abufA = (float*)vA;      // forward a1: f32 [16][132] = 8448 B (aliased, sync-separated)
    float* abufB = (float*)vB;      // forward a2

    const int tid  = threadIdx.x;
    const int s    = tid & 15;      // sample (forward phase)
    const int gg   = tid >> 4;      // unit group 0..15 (8 units each)
    const int i0   = gg * 8;
    const long sg0 = (long)blockIdx.x * SAMP;
    const bool valid = (sg0 + s < (long)Btot);

    float4 uv = make_float4(0.f, 0.f, 0.f, 0.f);
    if (valid) uv = *(const float4*)(u + (sg0 + s) * 4);

    // ======== forward layer 1 (bit-exact: seq f32 fma chain from 0, bias after) ========
    {
        unsigned m = 0;
        #pragma unroll
        for (int ii = 0; ii < 8; ++ii) {
            const int i = i0 + ii;
            const float4 w = *(const float4*)(W1 + i * 4);
            float h = 0.f;
            h = fmaf(w.x, uv.x, h);
            h = fmaf(w.y, uv.y, h);
            h = fmaf(w.z, uv.z, h);
            h = fmaf(w.w, uv.w, h);
            h = h + b1[i];
            if (h > 0.f) m |= (1u << ii);
            abufA[s * ASTR + i] = fmaxf(h, 0.f);
        }
        mlds[0][s][gg] = (unsigned char)m;
    }
    __syncthreads();   // B1

    // ======== forward layer 2 ========
    {
        float acc[8];
        #pragma unroll
        for (int ii = 0; ii < 8; ++ii) acc[ii] = 0.f;
        const float* arow = abufA + s * ASTR;
        #pragma unroll 2
        for (int jc = 0; jc < 32; ++jc) {
            const float4 av = *(const float4*)(arow + jc * 4);
            #pragma unroll
            for (int ii = 0; ii < 8; ++ii) {
                const float4 w = *(const float4*)(W2 + (i0 + ii) * HIDN + jc * 4);
                float a = acc[ii];
                a = fmaf(w.x, av.x, a);
                a = fmaf(w.y, av.y, a);
                a = fmaf(w.z, av.z, a);
                a = fmaf(w.w, av.w, a);
                acc[ii] = a;
            }
        }
        unsigned m = 0;
        #pragma unroll
        for (int ii = 0; ii < 8; ++ii) {
            const float h = acc[ii] + b2[i0 + ii];
            if (h > 0.f) m |= (1u << ii);
            abufB[s * ASTR + i0 + ii] = fmaxf(h, 0.f);   // other buffer: no WAR on abufA
        }
        mlds[1][s][gg] = (unsigned char)m;
    }
    __syncthreads();   // B2

    // ======== forward layer 3 (mask only) ========
    {
        float acc[8];
        #pragma unroll
        for (int ii = 0; ii < 8; ++ii) acc[ii] = 0.f;
        const float* arow = abufB + s * ASTR;
        #pragma unroll 2
        for (int jc = 0; jc < 32; ++jc) {
            const float4 av = *(const float4*)(arow + jc * 4);
            #pragma unroll
            for (int ii = 0; ii < 8; ++ii) {
                const float4 w = *(const float4*)(W3 + (i0 + ii) * HIDN + jc * 4);
                float a = acc[ii];
                a = fmaf(w.x, av.x, a);
                a = fmaf(w.y, av.y, a);
                a = fmaf(w.z, av.z, a);
                a = fmaf(w.w, av.w, a);
                acc[ii] = a;
            }
        }
        unsigned m = 0;
        #pragma unroll
        for (int ii = 0; ii < 8; ++ii) {
            const float h = acc[ii] + b3[i0 + ii];
            if (h > 0.f) m |= (1u << ii);
        }
        mlds[2][s][gg] = (unsigned char)m;
    }
    __syncthreads();   // B3 — last barrier before epilogue (tangent chain is wave-private)

    // ======== v1 build: vA row sc=s*4+c = bf16(m1[s][j] * W1[j][c]) ========
    {
        const int row = tid >> 2, kq = tid & 3;   // wave wv writes rows [wv*16, wv*16+16)
        const int vs = row >> 2, vc = row & 3;
        const unsigned short* w1t = wsb + WS_W1T + vc * HIDN;
        #pragma unroll
        for (int t = 0; t < 4; ++t) {
            const int j0 = kq * 32 + t * 8;
            const short8 w = *(const short8*)(w1t + j0);
            short8 fr;
            #pragma unroll
            for (int e = 0; e < 8; ++e) {
                const int j = j0 + e;
                fr[e] = ((mlds[0][vs][j >> 3] >> (j & 7)) & 1u) ? w[e] : (short)0;
            }
            *(short8*)(vA + row * VSTR + j0 * 2) = fr;
        }
    }

    const int lane = tid & 63, wv = tid >> 6;
    const int lr = lane & 15, lk = lane >> 4;

    // ======== tangent layers 2,3 (ping-pong vA -> vB -> vA; no barriers: wave-private rows) ========
    tangent_layer(vA, vB, wsb + WS_W2, &mlds[1][0][0], wv, lr, lk);
    tangent_layer(vB, vA, wsb + WS_W3, &mlds[2][0][0], wv, lr, lk);

    // ======== Jf: D[c'][sc] = sum_j W4[c'][j] * V3[sc][j] (W4b rows 4..15 zero) ========
    {
        short8 a4[4], b[4];
        #pragma unroll
        for (int ks = 0; ks < 4; ++ks) {
            a4[ks] = *(const short8*)(wsb + WS_W4 + lr * HIDN + ks * 32 + lk * 8);
            b[ks]  = *(const short8*)(vA + (wv * 16 + lr) * VSTR + ks * 64 + lk * 16);
        }
        f32x4 c = (f32x4){0.f, 0.f, 0.f, 0.f};
        #pragma unroll
        for (int ks = 0; ks < 4; ++ks)
            c = __builtin_amdgcn_mfma_f32_16x16x32_bf16(a4[ks], b[ks], c, 0, 0, 0);
        if (lk == 0) {   // c' = lk*4+r = r (0..3); sc = wv*16+lr
            const int sc = wv * 16 + lr;
            #pragma unroll
            for (int r = 0; r < 4; ++r)
                jbuf[sc * 5 + r] = c[r];
        }
    }
    __syncthreads();   // B4 — jbuf cross-wave before epilogue

    // ======== epilogue: out[s][a][b'] = Jf[b'][a] - Jf[a][b']; Jf[c'][c] = jbuf[(s*4+c)*5+c'] ========
    if (tid < 64) {
        const int es = tid >> 2, ea = tid & 3;
        if (sg0 + es < (long)Btot) {
            float4 o;
            o.x = jbuf[(es * 4 + ea) * 5 + 0] - jbuf[(es * 4 + 0) * 5 + ea];
            o.y = jbuf[(es * 4 + ea) * 5 + 1] - jbuf[(es * 4 + 1) * 5 + ea];
            o.z = jbuf[(es * 4 + ea) * 5 + 2] - jbuf[(es * 4 + 2) * 5 + ea];
            o.w = jbuf[(es * 4 + ea) * 5 + 3] - jbuf[(es * 4 + 3) * 5 + ea];
            *(float4*)(out + (sg0 + es) * 16 + ea * 4) = o;
        }
    }
}

extern "C" void kernel_launch(void* const* d_in, const int* in_sizes, int n_in,
                              void* d_out, int out_size, void* d_ws, size_t ws_size,
                              hipStream_t stream)
{
    const float* u  = (const float*)d_in[0];
    const float* W1 = (const float*)d_in[1];
    const float* b1 = (const float*)d_in[2];
    const float* W2 = (const float*)d_in[3];
    const float* b2 = (const float*)d_in[4];
    const float* W3 = (const float*)d_in[5];
    const float* b3 = (const float*)d_in[6];
    const float* W4 = (const float*)d_in[7];
    // d_in[8] = b4: unused (bias does not enter the Jacobian)
    float* out = (float*)d_out;
    unsigned short* wsb = (unsigned short*)d_ws;   // needs 70656 B

    const int B = in_sizes[0] / 4;
    hipLaunchKernelGGL(conv_w_kernel, dim3((WS_TOT + 255) / 256), dim3(256), 0, stream,
                       W1, W2, W3, W4, wsb);
    const int nblocks = (B + SAMP - 1) / SAMP;
    hipLaunchKernelGGL(wnn_jac_kernel, dim3(nblocks), dim3(256), 0, stream,
                       u, W1, b1, W2, b2, W3, b3, wsb, out, B);
}

// Round 10
// 710.127 us; speedup vs baseline: 5.2240x; 1.0026x over previous
//
#include <hip/hip_runtime.h>

#define HIDN 128
#define SAMP 16            // samples per block
#define VSTR 272           // V-buffer row stride in BYTES (17x16B -> conflict-free b128)
#define ASTR 132           // f32 activation row stride (floats)

typedef __attribute__((ext_vector_type(8))) short short8;
typedef __attribute__((ext_vector_type(4))) float f32x4;

// ws layout (ushort units): [0,16384) W2b[128][128]; [16384,32768) W3b[128][128];
// [32768,34816) W4b[16][128] (rows 4..15 zero); [34816,35328) W1Tb[4][128]
#define WS_W2 0
#define WS_W3 16384
#define WS_W4 32768
#define WS_W1T 34816
#define WS_TOT 35328

// f32 -> bf16 round-to-nearest-even
__device__ __forceinline__ unsigned short f2bf(float f) {
    unsigned b = __float_as_uint(f);
    b += 0x7FFFu + ((b >> 16) & 1u);
    return (unsigned short)(b >> 16);
}

// ---------- prelude: one-time weight conversion to bf16 into ws ----------
__global__ void conv_w_kernel(const float* __restrict__ W1, const float* __restrict__ W2,
                              const float* __restrict__ W3, const float* __restrict__ W4,
                              unsigned short* __restrict__ wsb)
{
    const int idx = blockIdx.x * 256 + threadIdx.x;
    if (idx < 16384) {
        wsb[idx] = f2bf(W2[idx]);
    } else if (idx < 32768) {
        wsb[idx] = f2bf(W3[idx - 16384]);
    } else if (idx < 34816) {
        const int r = (idx - 32768) >> 7, j = (idx - 32768) & 127;
        wsb[idx] = (r < 4) ? f2bf(W4[r * HIDN + j]) : (unsigned short)0;
    } else if (idx < WS_TOT) {
        const int c = (idx - 34816) >> 7, j = (idx - 34816) & 127;
        wsb[idx] = f2bf(W1[j * 4 + c]);
    }
}

// One tangent layer, PING-PONG (src != dst; in-place corrupts — R6/R8 lesson, 2-for-2).
// Wave owns V rows [wv*16, wv*16+16). A = W rows (bf16 from ws), B = V cols.
// D[m=unit ib*16+lk*4+r][n=sc=wv*16+lr] -> one b64 store per (ib).
__device__ __forceinline__ void tangent_layer(const unsigned char* __restrict__ src,
                                              unsigned char* __restrict__ dst,
                                              const unsigned short* __restrict__ Wb,
                                              const unsigned char* __restrict__ msk, // [16][16]
                                              int wv, int lr, int lk)
{
    short8 b[4];
    #pragma unroll
    for (int ks = 0; ks < 4; ++ks)
        b[ks] = *(const short8*)(src + (wv * 16 + lr) * VSTR + ks * 64 + lk * 16);

    const int sc = wv * 16 + lr;
    #pragma unroll
    for (int ib = 0; ib < 8; ++ib) {
        short8 a[4];
        #pragma unroll
        for (int ks = 0; ks < 4; ++ks)
            a[ks] = *(const short8*)(Wb + (ib * 16 + lr) * HIDN + ks * 32 + lk * 8);
        f32x4 c = (f32x4){0.f, 0.f, 0.f, 0.f};
        #pragma unroll
        for (int ks = 0; ks < 4; ++ks)
            c = __builtin_amdgcn_mfma_f32_16x16x32_bf16(a[ks], b[ks], c, 0, 0, 0);
        // units i = ib*16 + lk*4 + r ; mask byte (i>>3), bit (i&7)
        const unsigned bits = (msk[(sc >> 2) * 16 + ib * 2 + (lk >> 1)] >> ((lk & 1) * 4)) & 0xFu;
        unsigned long long pk = 0;
        #pragma unroll
        for (int r = 0; r < 4; ++r) {
            const unsigned short v = ((bits >> r) & 1u) ? f2bf(c[r]) : (unsigned short)0;
            pk |= (unsigned long long)v << (r * 16);
        }
        *(unsigned long long*)(dst + sc * VSTR + ib * 32 + lk * 8) = pk;
    }
}

__global__ __launch_bounds__(256, 4)
void wnn_jac_kernel(const float* __restrict__ u,
                    const float* __restrict__ W1, const float* __restrict__ b1,
                    const float* __restrict__ W2, const float* __restrict__ b2,
                    const float* __restrict__ W3, const float* __restrict__ b3,
                    const unsigned short* __restrict__ wsb,
                    float* __restrict__ out, int Btot)
{
    __shared__ __align__(16) unsigned char vA[64 * VSTR];   // 17408 B
    __shared__ __align__(16) unsigned char vB[64 * VSTR];   // 17408 B
    __shared__ unsigned char mlds[3][SAMP][16];             // 768 B
    __shared__ float jbuf[64 * 5];                          // 1280 B  -> total 36864 B, 4 blocks/CU

    float* abufA = (float*)vA;      // forward a1: f32 [16][132] = 8448 B (aliased, sync-separated)
    float* abufB = (float*)vB;      // forward a2

    const int tid  = threadIdx.x;
    const int s    = tid & 15;      // sample (forward phase)
    const int gg   = tid >> 4;      // unit group 0..15 (8 units each)
    const int i0   = gg * 8;
    const long sg0 = (long)blockIdx.x * SAMP;
    const bool valid = (sg0 + s < (long)Btot);

    float4 uv = make_float4(0.f, 0.f, 0.f, 0.f);
    if (valid) uv = *(const float4*)(u + (sg0 + s) * 4);

    // ======== forward layer 1 (bit-exact: seq f32 fma chain from 0, bias after) ========
    {
        unsigned m = 0;
        #pragma unroll
        for (int ii = 0; ii < 8; ++ii) {
            const int i = i0 + ii;
            const float4 w = *(const float4*)(W1 + i * 4);
            float h = 0.f;
            h = fmaf(w.x, uv.x, h);
            h = fmaf(w.y, uv.y, h);
            h = fmaf(w.z, uv.z, h);
            h = fmaf(w.w, uv.w, h);
            h = h + b1[i];
            if (h > 0.f) m |= (1u << ii);
            abufA[s * ASTR + i] = fmaxf(h, 0.f);
        }
        mlds[0][s][gg] = (unsigned char)m;
    }
    __syncthreads();   // B1

    // ======== forward layer 2 (unroll 4: ~36 independent loads hoistable per window) ========
    {
        float acc[8];
        #pragma unroll
        for (int ii = 0; ii < 8; ++ii) acc[ii] = 0.f;
        const float* arow = abufA + s * ASTR;
        #pragma unroll 4
        for (int jc = 0; jc < 32; ++jc) {
            const float4 av = *(const float4*)(arow + jc * 4);
            #pragma unroll
            for (int ii = 0; ii < 8; ++ii) {
                const float4 w = *(const float4*)(W2 + (i0 + ii) * HIDN + jc * 4);
                float a = acc[ii];
                a = fmaf(w.x, av.x, a);
                a = fmaf(w.y, av.y, a);
                a = fmaf(w.z, av.z, a);
                a = fmaf(w.w, av.w, a);
                acc[ii] = a;
            }
        }
        unsigned m = 0;
        #pragma unroll
        for (int ii = 0; ii < 8; ++ii) {
            const float h = acc[ii] + b2[i0 + ii];
            if (h > 0.f) m |= (1u << ii);
            abufB[s * ASTR + i0 + ii] = fmaxf(h, 0.f);   // other buffer: no WAR on abufA
        }
        mlds[1][s][gg] = (unsigned char)m;
    }
    __syncthreads();   // B2

    // ======== forward layer 3 (mask only, unroll 4) ========
    {
        float acc[8];
        #pragma unroll
        for (int ii = 0; ii < 8; ++ii) acc[ii] = 0.f;
        const float* arow = abufB + s * ASTR;
        #pragma unroll 4
        for (int jc = 0; jc < 32; ++jc) {
            const float4 av = *(const float4*)(arow + jc * 4);
            #pragma unroll
            for (int ii = 0; ii < 8; ++ii) {
                const float4 w = *(const float4*)(W3 + (i0 + ii) * HIDN + jc * 4);
                float a = acc[ii];
                a = fmaf(w.x, av.x, a);
                a = fmaf(w.y, av.y, a);
                a = fmaf(w.z, av.z, a);
                a = fmaf(w.w, av.w, a);
                acc[ii] = a;
            }
        }
        unsigned m = 0;
        #pragma unroll
        for (int ii = 0; ii < 8; ++ii) {
            const float h = acc[ii] + b3[i0 + ii];
            if (h > 0.f) m |= (1u << ii);
        }
        mlds[2][s][gg] = (unsigned char)m;
    }
    __syncthreads();   // B3 — last barrier before epilogue (tangent chain is wave-private)

    // ======== v1 build: vA row sc=s*4+c = bf16(m1[s][j] * W1[j][c]) ========
    {
        const int row = tid >> 2, kq = tid & 3;   // wave wv writes rows [wv*16, wv*16+16)
        const int vs = row >> 2, vc = row & 3;
        const unsigned short* w1t = wsb + WS_W1T + vc * HIDN;
        #pragma unroll
        for (int t = 0; t < 4; ++t) {
            const int j0 = kq * 32 + t * 8;
            const short8 w = *(const short8*)(w1t + j0);
            short8 fr;
            #pragma unroll
            for (int e = 0; e < 8; ++e) {
                const int j = j0 + e;
                fr[e] = ((mlds[0][vs][j >> 3] >> (j & 7)) & 1u) ? w[e] : (short)0;
            }
            *(short8*)(vA + row * VSTR + j0 * 2) = fr;
        }
    }

    const int lane = tid & 63, wv = tid >> 6;
    const int lr = lane & 15, lk = lane >> 4;

    // ======== tangent layers 2,3 (ping-pong vA -> vB -> vA; no barriers: wave-private rows) ========
    tangent_layer(vA, vB, wsb + WS_W2, &mlds[1][0][0], wv, lr, lk);
    tangent_layer(vB, vA, wsb + WS_W3, &mlds[2][0][0], wv, lr, lk);

    // ======== Jf: D[c'][sc] = sum_j W4[c'][j] * V3[sc][j] (W4b rows 4..15 zero) ========
    {
        short8 a4[4], b[4];
        #pragma unroll
        for (int ks = 0; ks < 4; ++ks) {
            a4[ks] = *(const short8*)(wsb + WS_W4 + lr * HIDN + ks * 32 + lk * 8);
            b[ks]  = *(const short8*)(vA + (wv * 16 + lr) * VSTR + ks * 64 + lk * 16);
        }
        f32x4 c = (f32x4){0.f, 0.f, 0.f, 0.f};
        #pragma unroll
        for (int ks = 0; ks < 4; ++ks)
            c = __builtin_amdgcn_mfma_f32_16x16x32_bf16(a4[ks], b[ks], c, 0, 0, 0);
        if (lk == 0) {   // c' = lk*4+r = r (0..3); sc = wv*16+lr
            const int sc = wv * 16 + lr;
            #pragma unroll
            for (int r = 0; r < 4; ++r)
                jbuf[sc * 5 + r] = c[r];
        }
    }
    __syncthreads();   // B4 — jbuf cross-wave before epilogue

    // ======== epilogue: out[s][a][b'] = Jf[b'][a] - Jf[a][b']; Jf[c'][c] = jbuf[(s*4+c)*5+c'] ========
    if (tid < 64) {
        const int es = tid >> 2, ea = tid & 3;
        if (sg0 + es < (long)Btot) {
            float4 o;
            o.x = jbuf[(es * 4 + ea) * 5 + 0] - jbuf[(es * 4 + 0) * 5 + ea];
            o.y = jbuf[(es * 4 + ea) * 5 + 1] - jbuf[(es * 4 + 1) * 5 + ea];
            o.z = jbuf[(es * 4 + ea) * 5 + 2] - jbuf[(es * 4 + 2) * 5 + ea];
            o.w = jbuf[(es * 4 + ea) * 5 + 3] - jbuf[(es * 4 + 3) * 5 + ea];
            *(float4*)(out + (sg0 + es) * 16 + ea * 4) = o;
        }
    }
}

extern "C" void kernel_launch(void* const* d_in, const int* in_sizes, int n_in,
                              void* d_out, int out_size, void* d_ws, size_t ws_size,
                              hipStream_t stream)
{
    const float* u  = (const float*)d_in[0];
    const float* W1 = (const float*)d_in[1];
    const float* b1 = (const float*)d_in[2];
    const float* W2 = (const float*)d_in[3];
    const float* b2 = (const float*)d_in[4];
    const float* W3 = (const float*)d_in[5];
    const float* b3 = (const float*)d_in[6];
    const float* W4 = (const float*)d_in[7];
    // d_in[8] = b4: unused (bias does not enter the Jacobian)
    float* out = (float*)d_out;
    unsigned short* wsb = (unsigned short*)d_ws;   // needs 70656 B

    const int B = in_sizes[0] / 4;
    hipLaunchKernelGGL(conv_w_kernel, dim3((WS_TOT + 255) / 256), dim3(256), 0, stream,
                       W1, W2, W3, W4, wsb);
    const int nblocks = (B + SAMP - 1) / SAMP;
    hipLaunchKernelGGL(wnn_jac_kernel, dim3(nblocks), dim3(256), 0, stream,
                       u, W1, b1, W2, b2, W3, b3, wsb, out, B);
}